// Round 1
// baseline (1519.207 us; speedup 1.0000x reference)
//
#include <hip/hip_runtime.h>

#define BATCH 32
#define HID   128
#define EMB   64
#define DEPTHS 32
#define NODES 512
#define PAR   8
#define OUTROWS 16385                 // 1 + D*N  (slot s of ref buf -> out row s-1)
#define ROWSTRIDE ((size_t)OUTROWS * HID)

// out[b][0][:] = embedding[b][:]   (root, slot 1)
__global__ void __launch_bounds__(256) init_kernel(const float* __restrict__ emb,
                                                   float* __restrict__ out) {
    int i = blockIdx.x * 256 + threadIdx.x;      // 0..4095
    int b = i >> 7, h = i & 127;
    out[(size_t)b * ROWSTRIDE + h] = emb[i];
}

// One depth step. Block = 32 rows (one batch, consecutive n), 256 threads.
__global__ void __launch_bounds__(256) depth_kernel(
    float* __restrict__ buf,                 // d_out, [B][16385][128]
    const float* __restrict__ emb_table,     // [16386][64]
    const float* __restrict__ W1,            // [128][192]
    const float* __restrict__ b1,            // [128]
    const float* __restrict__ W2,            // [128][128]
    const float* __restrict__ b2,            // [128]
    const int*   __restrict__ parent_idx,    // [32][512][8]
    int d)
{
    __shared__ float xs[32][200];   // [row][0:128]=pv, [128:192]=node emb; stride 200 (800B, 16B-aligned)
    __shared__ float hs[32][132];   // relu(GEMM1) output
    __shared__ float ws[32][132];   // staged W^T k-tile: ws[k][c]

    const int t  = threadIdx.x;
    const int m0 = blockIdx.x * 32;          // global row tile start
    const int b  = m0 >> 9;                  // /512 : batch
    const int n0 = m0 & 511;                 // node tile start
    float* __restrict__ bbase = buf + (size_t)b * ROWSTRIDE;

    // ---------- gather: pv = sum_p buf[parent], plus node embedding ----------
    {
        const int lane = t & 31;             // 32 threads per row, float4 each
        const int rsub = t >> 5;             // 0..7
        for (int rc = 0; rc < 32; rc += 8) {
            const int r = rc + rsub;
            const int* pp = parent_idx + ((d * NODES) + (n0 + r)) * PAR;
            float4 acc = make_float4(0.f, 0.f, 0.f, 0.f);
            #pragma unroll
            for (int p = 0; p < PAR; ++p) {
                const int s = pp[p];
                if (s > 0) {                 // slot 0 = padding (zeros)
                    const float4 v = *(const float4*)(bbase + (size_t)(s - 1) * HID + lane * 4);
                    acc.x += v.x; acc.y += v.y; acc.z += v.z; acc.w += v.w;
                }
            }
            *(float4*)&xs[r][lane * 4] = acc;
        }
        // node embeddings -> xs[r][128..191]; table rows are contiguous here
        const int base_row = 2 + d * NODES + n0;
        for (int i = t; i < 32 * 16; i += 256) {
            const int r = i >> 4, e4 = i & 15;
            const float4 v = *(const float4*)(emb_table + (size_t)(base_row + r) * EMB + e4 * 4);
            *(float4*)&xs[r][128 + e4 * 4] = v;
        }
    }
    __syncthreads();

    const int tc = t & 31, tr = t >> 5;      // 32 col-groups x 8 row-groups
    const int c0 = tc * 4, r0 = tr * 4;      // each thread: 4 rows x 4 cols

    float acc[4][4];
    #pragma unroll
    for (int j = 0; j < 4; ++j)
        #pragma unroll
        for (int i = 0; i < 4; ++i) acc[j][i] = 0.f;

    // ---------- GEMM1: h = x[32x192] @ W1^T -> [32x128] ----------
    for (int k0 = 0; k0 < 192; k0 += 32) {
        // stage ws[k][c] = W1[c][k0+k]  (coalesced float4 reads along k)
        #pragma unroll
        for (int i0 = 0; i0 < 1024; i0 += 256) {
            const int i = i0 + t;
            const int c = i >> 3, k4 = i & 7;
            const float4 w = *(const float4*)(W1 + c * 192 + k0 + k4 * 4);
            ws[k4 * 4 + 0][c] = w.x;
            ws[k4 * 4 + 1][c] = w.y;
            ws[k4 * 4 + 2][c] = w.z;
            ws[k4 * 4 + 3][c] = w.w;
        }
        __syncthreads();
        #pragma unroll
        for (int kk = 0; kk < 32; kk += 4) {
            float4 xv[4], wv[4];
            #pragma unroll
            for (int j = 0; j < 4; ++j)
                xv[j] = *(const float4*)&xs[r0 + j][k0 + kk];
            #pragma unroll
            for (int q = 0; q < 4; ++q)
                wv[q] = *(const float4*)&ws[kk + q][c0];
            #pragma unroll
            for (int j = 0; j < 4; ++j) {
                const float xf[4] = {xv[j].x, xv[j].y, xv[j].z, xv[j].w};
                #pragma unroll
                for (int q = 0; q < 4; ++q) {
                    acc[j][0] = fmaf(xf[q], wv[q].x, acc[j][0]);
                    acc[j][1] = fmaf(xf[q], wv[q].y, acc[j][1]);
                    acc[j][2] = fmaf(xf[q], wv[q].z, acc[j][2]);
                    acc[j][3] = fmaf(xf[q], wv[q].w, acc[j][3]);
                }
            }
        }
        __syncthreads();
    }

    // bias + relu -> hs
    {
        const float4 bv = *(const float4*)(b1 + c0);
        #pragma unroll
        for (int j = 0; j < 4; ++j) {
            float4 h;
            h.x = fmaxf(acc[j][0] + bv.x, 0.f);
            h.y = fmaxf(acc[j][1] + bv.y, 0.f);
            h.z = fmaxf(acc[j][2] + bv.z, 0.f);
            h.w = fmaxf(acc[j][3] + bv.w, 0.f);
            *(float4*)&hs[r0 + j][c0] = h;
        }
    }
    __syncthreads();

    #pragma unroll
    for (int j = 0; j < 4; ++j)
        #pragma unroll
        for (int i = 0; i < 4; ++i) acc[j][i] = 0.f;

    // ---------- GEMM2: h2 = hs[32x128] @ W2^T -> [32x128] ----------
    for (int k0 = 0; k0 < 128; k0 += 32) {
        #pragma unroll
        for (int i0 = 0; i0 < 1024; i0 += 256) {
            const int i = i0 + t;
            const int c = i >> 3, k4 = i & 7;
            const float4 w = *(const float4*)(W2 + c * 128 + k0 + k4 * 4);
            ws[k4 * 4 + 0][c] = w.x;
            ws[k4 * 4 + 1][c] = w.y;
            ws[k4 * 4 + 2][c] = w.z;
            ws[k4 * 4 + 3][c] = w.w;
        }
        __syncthreads();
        #pragma unroll
        for (int kk = 0; kk < 32; kk += 4) {
            float4 xv[4], wv[4];
            #pragma unroll
            for (int j = 0; j < 4; ++j)
                xv[j] = *(const float4*)&hs[r0 + j][k0 + kk];
            #pragma unroll
            for (int q = 0; q < 4; ++q)
                wv[q] = *(const float4*)&ws[kk + q][c0];
            #pragma unroll
            for (int j = 0; j < 4; ++j) {
                const float xf[4] = {xv[j].x, xv[j].y, xv[j].z, xv[j].w};
                #pragma unroll
                for (int q = 0; q < 4; ++q) {
                    acc[j][0] = fmaf(xf[q], wv[q].x, acc[j][0]);
                    acc[j][1] = fmaf(xf[q], wv[q].y, acc[j][1]);
                    acc[j][2] = fmaf(xf[q], wv[q].z, acc[j][2]);
                    acc[j][3] = fmaf(xf[q], wv[q].w, acc[j][3]);
                }
            }
        }
        __syncthreads();
    }

    // ---------- epilogue: v = pv + (h2 + b2), store ----------
    {
        const float4 bv = *(const float4*)(b2 + c0);
        float* dst0 = bbase + (size_t)(1 + d * NODES + n0) * HID;
        #pragma unroll
        for (int j = 0; j < 4; ++j) {
            const int r = r0 + j;
            const float4 pv = *(const float4*)&xs[r][c0];
            float4 o;
            o.x = pv.x + acc[j][0] + bv.x;
            o.y = pv.y + acc[j][1] + bv.y;
            o.z = pv.z + acc[j][2] + bv.z;
            o.w = pv.w + acc[j][3] + bv.w;
            *(float4*)(dst0 + (size_t)r * HID + c0) = o;
        }
    }
}

extern "C" void kernel_launch(void* const* d_in, const int* in_sizes, int n_in,
                              void* d_out, int out_size, void* d_ws, size_t ws_size,
                              hipStream_t stream) {
    const float* embedding  = (const float*)d_in[0];
    const float* emb_table  = (const float*)d_in[1];
    const float* W1         = (const float*)d_in[2];
    const float* b1         = (const float*)d_in[3];
    const float* W2         = (const float*)d_in[4];
    const float* b2         = (const float*)d_in[5];
    const int*   parent_idx = (const int*)d_in[6];
    float* out = (float*)d_out;

    init_kernel<<<16, 256, 0, stream>>>(embedding, out);
    for (int d = 0; d < DEPTHS; ++d) {
        depth_kernel<<<512, 256, 0, stream>>>(out, emb_table, W1, b1, W2, b2,
                                              parent_idx, d);
    }
}

// Round 2
// 1210.807 us; speedup vs baseline: 1.2547x; 1.2547x over previous
//
#include <hip/hip_runtime.h>

#define BATCH 32
#define HID   128
#define EMB   64
#define DEPTHS 32
#define NODES 512
#define PAR   8
#define OUTROWS 16385                 // 1 + D*N  (slot s of ref buf -> out row s-1)
#define ROWSTRIDE ((size_t)OUTROWS * HID)

typedef short bf16x8 __attribute__((ext_vector_type(8)));
typedef float f32x4  __attribute__((ext_vector_type(4)));

// ws layout (ushort elements): W1h[24576] | W1l[24576] | W2h[16384] | W2l[16384]
#define WS_W1L 24576
#define WS_W2H 49152
#define WS_W2L 65536
#define WS_BYTES 163840

// x = hi + lo, both bf16 (truncation split: combined rel err ~2^-17)
__device__ __forceinline__ void split1(float x, unsigned short& h, unsigned short& l) {
    unsigned u  = __float_as_uint(x);
    unsigned hu = u & 0xFFFF0000u;
    h = (unsigned short)(hu >> 16);
    float r = x - __uint_as_float(hu);
    l = (unsigned short)(__float_as_uint(r) >> 16);
}

// out[b][0][:] = embedding[b][:]   (root, slot 1)
__global__ void __launch_bounds__(256) init_kernel(const float* __restrict__ emb,
                                                   float* __restrict__ out) {
    int i = blockIdx.x * 256 + threadIdx.x;      // 0..4095
    int b = i >> 7, h = i & 127;
    out[(size_t)b * ROWSTRIDE + h] = emb[i];
}

// split W1,W2 into bf16 hi/lo in ws (runs every launch; ws is re-poisoned)
__global__ void __launch_bounds__(256) prep_kernel(const float* __restrict__ W1f,
                                                   const float* __restrict__ W2f,
                                                   unsigned short* __restrict__ wsw) {
    int i = blockIdx.x * 256 + threadIdx.x;      // 0..40959
    unsigned short h, l;
    if (i < 24576) {
        split1(W1f[i], h, l);
        wsw[i] = h; wsw[WS_W1L + i] = l;
    } else {
        int j = i - 24576;                        // 0..16383
        split1(W2f[j], h, l);
        wsw[WS_W2H + j] = h; wsw[WS_W2L + j] = l;
    }
}

// One depth step. Block = 16 rows (one batch, consecutive nodes), 256 threads = 4 waves.
// LDS strides: xs 204 f32 (16B-aligned rows); xh/xl 216 u16 (432B rows, 2-way banks);
// hh/hl 136 u16 (272B rows, 2-way banks); os 132 f32.
__global__ void __launch_bounds__(256) depth_kernel(
    float* __restrict__ buf,                 // d_out, [B][16385][128]
    const float* __restrict__ emb_table,     // [16386][64]
    const float* __restrict__ W1f,           // [128][192]
    const float* __restrict__ b1,            // [128]
    const float* __restrict__ W2f,           // [128][128]
    const float* __restrict__ b2,            // [128]
    const int*   __restrict__ parent_idx,    // [32][512][8]
    const unsigned short* __restrict__ wsw,  // split weights (if use_ws)
    int d, int use_ws)
{
    __shared__ __align__(16) char smem[13056 + 13824];
    float* xs = (float*)smem;                       // [16][204]: 0..127 pv, 128..191 emb

    const int t   = threadIdx.x;
    const int blk = blockIdx.x;                     // 0..1023
    const int b   = blk >> 5;                       // batch
    const int n0  = (blk & 31) << 4;                // node tile start (16 nodes)
    float* __restrict__ bbase = buf + (size_t)b * ROWSTRIDE;

    // ---------- gather pv + node embedding into xs ----------
    {
        const int lane = t & 31, rsub = t >> 5;     // 32 lanes per row
        for (int rr = rsub; rr < 16; rr += 8) {
            const int* pp = parent_idx + ((d << 9) + n0 + rr) * PAR;
            float4 a = make_float4(0.f, 0.f, 0.f, 0.f);
            #pragma unroll
            for (int p = 0; p < PAR; ++p) {
                const int s = pp[p];
                if (s > 0) {
                    const float4 v = *(const float4*)(bbase + (size_t)(s - 1) * HID + lane * 4);
                    a.x += v.x; a.y += v.y; a.z += v.z; a.w += v.w;
                }
            }
            *(float4*)&xs[rr * 204 + lane * 4] = a;
        }
        const int base_row = 2 + (d << 9) + n0;
        const int r = t >> 4, e4 = t & 15;
        *(float4*)&xs[r * 204 + 128 + e4 * 4] =
            *(const float4*)(emb_table + (size_t)(base_row + r) * EMB + e4 * 4);
    }
    __syncthreads();

    // ---------- split x -> bf16 hi/lo (once per element) ----------
    unsigned short* xh = (unsigned short*)(smem + 13056);
    unsigned short* xl = xh + 16 * 216;
    {
        const int r = t >> 4, cs = (t & 15) * 12;   // 16 threads/row x 12 cols = 192
        #pragma unroll
        for (int j = 0; j < 12; ++j) {
            unsigned short h, l;
            split1(xs[r * 204 + cs + j], h, l);
            xh[r * 216 + cs + j] = h;
            xl[r * 216 + cs + j] = l;
        }
    }
    __syncthreads();

    const int lane = t & 63, w = t >> 6;
    const int quad = lane >> 4, nib = lane & 15;

    // ---------- GEMM1: h = x[16x192] @ W1^T via MFMA ----------
    f32x4 acc1[2] = {{0.f,0.f,0.f,0.f},{0.f,0.f,0.f,0.f}};
    for (int k0 = 0; k0 < 192; k0 += 32) {
        const int ko = k0 + quad * 8;
        const bf16x8 ah = *(const bf16x8*)(xh + nib * 216 + ko);
        const bf16x8 al = *(const bf16x8*)(xl + nib * 216 + ko);
        #pragma unroll
        for (int nt = 0; nt < 2; ++nt) {
            const int n = ((w << 1) + nt) * 16 + nib;
            bf16x8 bh, bl;
            if (use_ws) {
                bh = *(const bf16x8*)(wsw + n * 192 + ko);
                bl = *(const bf16x8*)(wsw + WS_W1L + n * 192 + ko);
            } else {
                const float4 f0 = *(const float4*)(W1f + n * 192 + ko);
                const float4 f1 = *(const float4*)(W1f + n * 192 + ko + 4);
                const float ff[8] = {f0.x,f0.y,f0.z,f0.w,f1.x,f1.y,f1.z,f1.w};
                #pragma unroll
                for (int j = 0; j < 8; ++j) {
                    unsigned short hq, lq; split1(ff[j], hq, lq);
                    bh[j] = (short)hq; bl[j] = (short)lq;
                }
            }
            acc1[nt] = __builtin_amdgcn_mfma_f32_16x16x32_bf16(ah, bh, acc1[nt], 0, 0, 0);
            acc1[nt] = __builtin_amdgcn_mfma_f32_16x16x32_bf16(ah, bl, acc1[nt], 0, 0, 0);
            acc1[nt] = __builtin_amdgcn_mfma_f32_16x16x32_bf16(al, bh, acc1[nt], 0, 0, 0);
        }
    }
    __syncthreads();   // all waves done reading xh/xl before aliasing with hh/hl

    // ---------- epilogue 1: bias+relu, split -> hh/hl ----------
    unsigned short* hh = (unsigned short*)(smem + 13056);
    unsigned short* hl = hh + 16 * 136;
    #pragma unroll
    for (int nt = 0; nt < 2; ++nt) {
        const int c = ((w << 1) + nt) * 16 + nib;
        const float bb = b1[c];
        #pragma unroll
        for (int reg = 0; reg < 4; ++reg) {
            const int r = quad * 4 + reg;
            float h = fmaxf(acc1[nt][reg] + bb, 0.f);
            unsigned short hq, lq; split1(h, hq, lq);
            hh[r * 136 + c] = hq;
            hl[r * 136 + c] = lq;
        }
    }
    __syncthreads();

    // ---------- GEMM2: h2 = h[16x128] @ W2^T via MFMA ----------
    f32x4 acc2[2] = {{0.f,0.f,0.f,0.f},{0.f,0.f,0.f,0.f}};
    for (int k0 = 0; k0 < 128; k0 += 32) {
        const int ko = k0 + quad * 8;
        const bf16x8 ah = *(const bf16x8*)(hh + nib * 136 + ko);
        const bf16x8 al = *(const bf16x8*)(hl + nib * 136 + ko);
        #pragma unroll
        for (int nt = 0; nt < 2; ++nt) {
            const int n = ((w << 1) + nt) * 16 + nib;
            bf16x8 bh, bl;
            if (use_ws) {
                bh = *(const bf16x8*)(wsw + WS_W2H + n * 128 + ko);
                bl = *(const bf16x8*)(wsw + WS_W2L + n * 128 + ko);
            } else {
                const float4 f0 = *(const float4*)(W2f + n * 128 + ko);
                const float4 f1 = *(const float4*)(W2f + n * 128 + ko + 4);
                const float ff[8] = {f0.x,f0.y,f0.z,f0.w,f1.x,f1.y,f1.z,f1.w};
                #pragma unroll
                for (int j = 0; j < 8; ++j) {
                    unsigned short hq, lq; split1(ff[j], hq, lq);
                    bh[j] = (short)hq; bl[j] = (short)lq;
                }
            }
            acc2[nt] = __builtin_amdgcn_mfma_f32_16x16x32_bf16(ah, bh, acc2[nt], 0, 0, 0);
            acc2[nt] = __builtin_amdgcn_mfma_f32_16x16x32_bf16(ah, bl, acc2[nt], 0, 0, 0);
            acc2[nt] = __builtin_amdgcn_mfma_f32_16x16x32_bf16(al, bh, acc2[nt], 0, 0, 0);
        }
    }
    __syncthreads();   // all waves done reading hh/hl before aliasing with os

    // ---------- epilogue 2: os = h2 + b2 ----------
    float* os = (float*)(smem + 13056);             // [16][132]
    #pragma unroll
    for (int nt = 0; nt < 2; ++nt) {
        const int c = ((w << 1) + nt) * 16 + nib;
        const float bb = b2[c];
        #pragma unroll
        for (int reg = 0; reg < 4; ++reg) {
            const int r = quad * 4 + reg;
            os[r * 132 + c] = acc2[nt][reg] + bb;
        }
    }
    __syncthreads();

    // ---------- merged store: v = pv + os, coalesced float4 ----------
    {
        const int r = t >> 4, c = (t & 15) * 8;
        float4 o0 = *(float4*)&os[r * 132 + c];
        float4 o1 = *(float4*)&os[r * 132 + c + 4];
        const float4 p0 = *(const float4*)&xs[r * 204 + c];
        const float4 p1 = *(const float4*)&xs[r * 204 + c + 4];
        o0.x += p0.x; o0.y += p0.y; o0.z += p0.z; o0.w += p0.w;
        o1.x += p1.x; o1.y += p1.y; o1.z += p1.z; o1.w += p1.w;
        float* dst = bbase + (size_t)(1 + (d << 9) + n0 + r) * HID + c;
        *(float4*)dst = o0;
        *(float4*)(dst + 4) = o1;
    }
}

extern "C" void kernel_launch(void* const* d_in, const int* in_sizes, int n_in,
                              void* d_out, int out_size, void* d_ws, size_t ws_size,
                              hipStream_t stream) {
    const float* embedding  = (const float*)d_in[0];
    const float* emb_table  = (const float*)d_in[1];
    const float* W1         = (const float*)d_in[2];
    const float* b1         = (const float*)d_in[3];
    const float* W2         = (const float*)d_in[4];
    const float* b2         = (const float*)d_in[5];
    const int*   parent_idx = (const int*)d_in[6];
    float* out = (float*)d_out;
    unsigned short* wsw = (unsigned short*)d_ws;
    const int use_ws = (ws_size >= (size_t)WS_BYTES) ? 1 : 0;

    init_kernel<<<16, 256, 0, stream>>>(embedding, out);
    if (use_ws) prep_kernel<<<160, 256, 0, stream>>>(W1, W2, wsw);
    for (int d = 0; d < DEPTHS; ++d) {
        depth_kernel<<<1024, 256, 0, stream>>>(out, emb_table, W1, b1, W2, b2,
                                               parent_idx, wsw, d, use_ws);
    }
}